// Round 12
// baseline (77.843 us; speedup 1.0000x reference)
//
#include <hip/hip_runtime.h>
#include <math.h>

// Problem constants (match reference)
#define BB   16
#define CC   64
#define LL   512
#define LP   16
#define DM   1024
#define NP   64
#define PRD  256   // period = L/2
#define HEAD 128   // PRD/2
#define NV   256   // L - PRD

typedef float f32x4 __attribute__((ext_vector_type(4)));

// workspace layout (in floats); all offsets 16B-aligned
#define OFF_MEANP 0                       // 8192
#define OFF_WSF   8192                    // 16*256 folded seasonal weights
#define OFF_WRS   12288                   // 16 resid weight sums
#define OFF_WGT   12304                   // 48*1024 transposed w_g

// ---------------------------------------------------------------------------
// Kernel 1: blocks 0..31 = per-(b,l) channel stats; block 32 = weight folding;
// blocks 33..48 = w_g transpose ([1024][48] -> [48][1024]). (identical to R10)
// ---------------------------------------------------------------------------
__global__ __launch_bounds__(256) void statsprep_kernel(
    const float* __restrict__ dx, const float* __restrict__ w_s,
    const float* __restrict__ w_r, const float* __restrict__ w_g,
    float* __restrict__ ws)
{
    const int tid = threadIdx.x, bid = blockIdx.x;
    if (bid < 32) {
        int id = bid * 256 + tid;            // 0..8191
        int b = id >> 9, l = id & 511;
        const float* p = dx + (size_t)b * CC * LL + l;
        float s = 0.f, sq = 0.f;
#pragma unroll 8
        for (int c = 0; c < CC; ++c) {
            float v = p[(size_t)c * LL];
            s += v; sq += v * v;
        }
        float mean = s * (1.0f / CC);
        float var  = (sq - (float)CC * mean * mean) * (1.0f / (CC - 1));
        ws[OFF_MEANP + id] = mean / sqrtf(var);
    } else if (bid == 32) {
        // fold seasonal weights: wsf[g][m] = w_s[g][m] + w_s[g][m+256]
#pragma unroll
        for (int idx = tid; idx < 16 * PRD; idx += 256) {
            int g = idx >> 8, m = idx & 255;
            ws[OFF_WSF + idx] = w_s[g * LL + m] + w_s[g * LL + PRD + m];
        }
        // resid weight sums: wrs[g] = sum w_r[g][128:384]
        int g = tid >> 4, ln = tid & 15;
        float s = 0.f;
        for (int k = ln; k < PRD; k += 16) s += w_r[g * LL + HEAD + k];
#pragma unroll
        for (int m = 8; m; m >>= 1) s += __shfl_xor(s, m, 16);
        if (ln == 0) ws[OFF_WRS + g] = s;
    } else {
        // transpose w_g: wgt[j*1024 + d] = w_g[d*48 + j]
        int base = (bid - 33) * 3072 + tid;
#pragma unroll
        for (int k = 0; k < 12; ++k) {
            int e = base + k * 256;          // e = j*1024 + d
            int j = e >> 10, d = e & 1023;
            ws[OFF_WGT + e] = w_g[d * 48 + j];
        }
    }
}

// ---------------------------------------------------------------------------
// Kernel 2 (fused, generational): 4096 blocks = (bc, d-quarter q).
// Each block: full (cheap) series pipeline -> matvec for its 256-wide d-slice
// (48 KB w_gT) -> store its 64 KB output slice. 16 blocks/CU => >=2
// generations resident: gen k+1 compute hides under gen k stores.
// ---------------------------------------------------------------------------
__global__ __launch_bounds__(256) void fused_kernel(
    const float* __restrict__ dx,    const float* __restrict__ gamma,
    const float* __restrict__ beta,  const float* __restrict__ w_t,
    const float* __restrict__ b_t,   const float* __restrict__ b_s,
    const float* __restrict__ b_r,   const float* __restrict__ b_g,
    const float* __restrict__ ws,    float* __restrict__ out)
{
    __shared__ __align__(16) float xs[LL];
    __shared__ __align__(16) float pps[LL/2 + 1];
    __shared__ __align__(16) float tvs[NV];
    __shared__ __align__(16) float pas[PRD];
    __shared__ __align__(16) float feats[48];
    __shared__ __align__(16) float sres[256];     // 1KB d-slice of result row
    __shared__ float wsum[4];
    __shared__ float wred[4];

    const int tid  = threadIdx.x;
    const int lane = tid & 63;
    const int wv   = tid >> 6;
    const int bc   = blockIdx.x >> 2;
    const int q    = blockIdx.x & 3;
    const int b    = bc >> 6;

    // transform (float2): x = gamma*(dx - meanp) + beta
    const size_t base = (size_t)bc * LL;
    float2 xv = ((const float2*)(dx    + base))[tid];
    float2 gv = ((const float2*)(gamma + base))[tid];
    float2 bv = ((const float2*)(beta  + base))[tid];
    float2 mv = ((const float2*)(ws + OFF_MEANP + (size_t)b * LL))[tid];
    float2 xp;
    xp.x = gv.x * (xv.x - mv.x) + bv.x;
    xp.y = gv.y * (xv.y - mv.y) + bv.y;
    ((float2*)xs)[tid] = xp;

    // inclusive scan of pair-sums (256 pairs)
    float v = xp.x + xp.y;
#pragma unroll
    for (int d = 1; d < 64; d <<= 1) {
        float t = __shfl_up(v, d, 64);
        if (lane >= d) v += t;
    }
    if (lane == 63) wsum[wv] = v;
    __syncthreads();
    float off = 0.f;
    for (int w = 0; w < wv; ++w) off += wsum[w];
    pps[tid + 1] = v + off;
    if (tid == 0) pps[0] = 0.f;
    __syncthreads();

    // trend via prefix sums
    const int i  = tid;
    const int k2 = i + 257;
    const float Pi = pps[i  >> 1] + ((i  & 1) ? xs[i  & ~1] : 0.f);
    const float Pk = pps[k2 >> 1] + ((k2 & 1) ? xs[k2 & ~1] : 0.f);
    const float tv = (Pk - Pi - 0.5f * (xs[i] + xs[i + 256])) * (1.0f / 256.0f);
    tvs[i] = tv;
    const float dv = xs[HEAD + i] - tv;

    // mdv = mean(dv)
    float r = dv;
#pragma unroll
    for (int m = 32; m; m >>= 1) r += __shfl_xor(r, m, 64);
    if (lane == 0) wred[wv] = r;
    __syncthreads();
    const float mdv = (wred[0] + wred[1] + wred[2] + wred[3]) * (1.0f / 256.0f);

    pas[(i + 128) & 255] = dv - mdv;
    __syncthreads();

    // feature dots with folded weights (8 float4 loads/thread)
    {
        const int g  = tid >> 4;
        const int ln = tid & 15;
        const f32x4* wt4  = (const f32x4*)(w_t + g * LL + HEAD);
        const f32x4* wsf4 = (const f32x4*)(ws + OFF_WSF + g * PRD);
        const f32x4* tv4  = (const f32x4*)tvs;
        const f32x4* pa4  = (const f32x4*)pas;
        float at = 0.f, as = 0.f;
#pragma unroll
        for (int qq = 0; qq < 4; ++qq) {
            const int m = ln * 4 + qq;
            f32x4 t = tv4[m], p = pa4[m];
            f32x4 a = wt4[m], sfw = wsf4[m];
            at += t.x * a.x + t.y * a.y + t.z * a.z + t.w * a.w;
            as += p.x * sfw.x + p.y * sfw.y + p.z * sfw.z + p.w * sfw.w;
        }
#pragma unroll
        for (int msk = 8; msk; msk >>= 1) {
            at += __shfl_xor(at, msk, 64);
            as += __shfl_xor(as, msk, 64);
        }
        if (ln == 0) {
            feats[g]      = at + b_t[g];
            feats[16 + g] = as + b_s[g];
            feats[32 + g] = mdv * ws[OFF_WRS + g] + b_r[g];
        }
    }
    __syncthreads();

    // ---- matvec for this block's d-slice: d = q*256 + tid (48 KB of w_gT)
    const int d = q * 256 + tid;
    const float* wT = ws + OFF_WGT + d;
    float acc = b_g[d];
#pragma unroll
    for (int j = 0; j < 48; ++j)
        acc = fmaf(feats[j], wT[j * DM], acc);
    sres[tid] = acc;
    __syncthreads();

    // ---- store 64 rows x 1KB slice. Wave wv owns rows [wv*16, wv*16+16).
    const f32x4 vv = ((const f32x4*)sres)[lane];
    f32x4* op = (f32x4*)out + (size_t)bc * (NP * DM / 4)
              + (size_t)(wv * 16) * (DM / 4) + q * 64 + lane;
#pragma unroll
    for (int n = 0; n < 16; ++n)
        op[n * (DM / 4)] = vv;
}

// ---------------------------------------------------------------------------
extern "C" void kernel_launch(void* const* d_in, const int* in_sizes, int n_in,
                              void* d_out, int out_size, void* d_ws, size_t ws_size,
                              hipStream_t stream) {
    const float* dx    = (const float*)d_in[0];
    const float* gamma = (const float*)d_in[1];
    const float* beta  = (const float*)d_in[2];
    const float* w_t   = (const float*)d_in[3];
    const float* b_t   = (const float*)d_in[4];
    const float* w_s   = (const float*)d_in[5];
    const float* b_s   = (const float*)d_in[6];
    const float* w_r   = (const float*)d_in[7];
    const float* b_r   = (const float*)d_in[8];
    const float* w_g   = (const float*)d_in[9];
    const float* b_g   = (const float*)d_in[10];
    float* out = (float*)d_out;
    float* ws  = (float*)d_ws;

    statsprep_kernel<<<49, 256, 0, stream>>>(dx, w_s, w_r, w_g, ws);
    fused_kernel<<<BB * CC * 4, 256, 0, stream>>>(
        dx, gamma, beta, w_t, b_t, b_s, b_r, b_g, ws, out);
}

// Round 13
// 66.681 us; speedup vs baseline: 1.1674x; 1.1674x over previous
//
#include <hip/hip_runtime.h>
#include <math.h>

// Problem constants (match reference)
#define BB   16
#define CC   64
#define LL   512
#define LP   16
#define DM   1024
#define NP   64
#define PRD  256   // period = L/2
#define HEAD 128   // PRD/2
#define NV   256   // L - PRD

typedef float f32x4 __attribute__((ext_vector_type(4)));

// workspace layout (floats)
#define OFF_WGT 0                        // 48*1024 transposed w_g

// ---------------------------------------------------------------------------
// Kernel 1: w_g transpose only. 16 blocks.
// wgt[j*1024 + d] = w_g[d*48 + j]
// ---------------------------------------------------------------------------
__global__ __launch_bounds__(256) void transpose_kernel(
    const float* __restrict__ w_g, float* __restrict__ ws)
{
    const int tid = threadIdx.x, bid = blockIdx.x;
    int base = bid * 3072 + tid;
#pragma unroll
    for (int k = 0; k < 12; ++k) {
        int e = base + k * 256;          // e = j*1024 + d
        int j = e >> 10, d = e & 1023;
        ws[OFF_WGT + e] = w_g[d * 48 + j];
    }
}

// ---------------------------------------------------------------------------
// Kernel 2 (fused): one block per (b,c).
// In-block coalesced channel stats -> transform -> scan decompose ->
// 48 features (LDS) -> f32x4 matvec vs transposed w_g (registers, no LDS
// stage) -> 64 broadcast row stores.
// ---------------------------------------------------------------------------
__global__ __launch_bounds__(256) void fused_kernel(
    const float* __restrict__ dx,    const float* __restrict__ gamma,
    const float* __restrict__ beta,  const float* __restrict__ w_t,
    const float* __restrict__ b_t,   const float* __restrict__ w_s,
    const float* __restrict__ b_s,   const float* __restrict__ w_r,
    const float* __restrict__ b_r,   const float* __restrict__ b_g,
    const float* __restrict__ ws,    float* __restrict__ out)
{
    __shared__ __align__(16) float xs[LL];
    __shared__ __align__(16) float pps[LL/2 + 1];
    __shared__ __align__(16) float tvs[NV];
    __shared__ __align__(16) float pas[PRD];
    __shared__ __align__(16) float feats[48];
    __shared__ float wsum[4];
    __shared__ float wred[4];

    const int tid  = threadIdx.x;
    const int lane = tid & 63;
    const int wv   = tid >> 6;
    const int bc   = blockIdx.x;
    const int b    = bc >> 6;
    const int cown = bc & 63;

    // ---- in-block channel stats (coalesced): thread owns l = 2tid, 2tid+1.
    // meanp_l = mean_c(dx[b,:,l]) / sqrt(var_c (ddof=1))
    const float2* dxb = (const float2*)(dx + (size_t)b * CC * LL);
    float2 sv = make_float2(0.f, 0.f), qv = make_float2(0.f, 0.f);
    float2 xv = make_float2(0.f, 0.f);           // own channel's value
#pragma unroll 8
    for (int c = 0; c < CC; ++c) {
        float2 v = dxb[c * 256 + tid];
        if (c == cown) xv = v;
        sv.x += v.x;       sv.y += v.y;
        qv.x += v.x * v.x; qv.y += v.y * v.y;
    }
    float2 mp;
    {
        float mx = sv.x * (1.0f / CC), my = sv.y * (1.0f / CC);
        float vx = (qv.x - (float)CC * mx * mx) * (1.0f / (CC - 1));
        float vy = (qv.y - (float)CC * my * my) * (1.0f / (CC - 1));
        mp.x = mx / sqrtf(vx);
        mp.y = my / sqrtf(vy);
    }

    // ---- transform (float2): x = gamma*(dx - meanp) + beta
    const size_t base = (size_t)bc * LL;
    float2 gv = ((const float2*)(gamma + base))[tid];
    float2 bv = ((const float2*)(beta  + base))[tid];
    float2 xp;
    xp.x = gv.x * (xv.x - mp.x) + bv.x;
    xp.y = gv.y * (xv.y - mp.y) + bv.y;
    ((float2*)xs)[tid] = xp;

    // ---- inclusive scan of pair-sums (256 pairs)
    float v = xp.x + xp.y;
#pragma unroll
    for (int d = 1; d < 64; d <<= 1) {
        float t = __shfl_up(v, d, 64);
        if (lane >= d) v += t;
    }
    if (lane == 63) wsum[wv] = v;
    __syncthreads();
    float off = 0.f;
    for (int w = 0; w < wv; ++w) off += wsum[w];
    pps[tid + 1] = v + off;
    if (tid == 0) pps[0] = 0.f;
    __syncthreads();

    // ---- trend via prefix sums
    const int i  = tid;
    const int k2 = i + 257;
    const float Pi = pps[i  >> 1] + ((i  & 1) ? xs[i  & ~1] : 0.f);
    const float Pk = pps[k2 >> 1] + ((k2 & 1) ? xs[k2 & ~1] : 0.f);
    const float tv = (Pk - Pi - 0.5f * (xs[i] + xs[i + 256])) * (1.0f / 256.0f);
    tvs[i] = tv;
    const float dv = xs[HEAD + i] - tv;

    // ---- mdv = mean(dv)
    float r = dv;
#pragma unroll
    for (int m = 32; m; m >>= 1) r += __shfl_xor(r, m, 64);
    if (lane == 0) wred[wv] = r;
    __syncthreads();
    const float mdv = (wred[0] + wred[1] + wred[2] + wred[3]) * (1.0f / 256.0f);

    pas[(i + 128) & 255] = dv - mdv;
    __syncthreads();

    // ---- feature dots, direct weights (R1-style, no prefold):
    // t: tvs . w_t[g,128:384]; s: pas . (w_s[g,0:256]+w_s[g,256:512]);
    // r: mdv * sum(w_r[g,128:384])
    {
        const int g  = tid >> 4;
        const int ln = tid & 15;
        const f32x4* wt4  = (const f32x4*)(w_t + g * LL + HEAD);
        const f32x4* ws4a = (const f32x4*)(w_s + g * LL);
        const f32x4* ws4b = (const f32x4*)(w_s + g * LL + PRD);
        const f32x4* wr4  = (const f32x4*)(w_r + g * LL + HEAD);
        const f32x4* tv4  = (const f32x4*)tvs;
        const f32x4* pa4  = (const f32x4*)pas;
        float at = 0.f, as = 0.f, ar = 0.f;
#pragma unroll
        for (int q = 0; q < 4; ++q) {
            const int m = ln * 4 + q;
            f32x4 t  = tv4[m],  p  = pa4[m];
            f32x4 a  = wt4[m];
            f32x4 s1 = ws4a[m], s2 = ws4b[m];
            f32x4 rr = wr4[m];
            at += t.x * a.x + t.y * a.y + t.z * a.z + t.w * a.w;
            as += p.x * (s1.x + s2.x) + p.y * (s1.y + s2.y)
                + p.z * (s1.z + s2.z) + p.w * (s1.w + s2.w);
            ar += rr.x + rr.y + rr.z + rr.w;
        }
#pragma unroll
        for (int msk = 8; msk; msk >>= 1) {
            at += __shfl_xor(at, msk, 64);
            as += __shfl_xor(as, msk, 64);
            ar += __shfl_xor(ar, msk, 64);
        }
        if (ln == 0) {
            feats[g]      = at + b_t[g];
            feats[16 + g] = as + b_s[g];
            feats[32 + g] = mdv * ar + b_r[g];
        }
    }
    __syncthreads();

    // ---- f32x4 matvec: thread owns d = 4*tid .. 4*tid+3.
    // 48 coalesced dwordx4 loads (1KB/wave-instr), acc in registers.
    const f32x4* wT4 = (const f32x4*)(ws + OFF_WGT);
    f32x4 acc = ((const f32x4*)b_g)[tid];
#pragma unroll
    for (int j = 0; j < 48; ++j)
        acc += feats[j] * wT4[j * 256 + tid];

    // ---- 64 broadcast row stores straight from registers (R10 pattern)
    f32x4* op = (f32x4*)out + (size_t)bc * (NP * DM / 4) + tid;
#pragma unroll
    for (int n = 0; n < NP; ++n)
        op[(size_t)n * (DM / 4)] = acc;
}

// ---------------------------------------------------------------------------
extern "C" void kernel_launch(void* const* d_in, const int* in_sizes, int n_in,
                              void* d_out, int out_size, void* d_ws, size_t ws_size,
                              hipStream_t stream) {
    const float* dx    = (const float*)d_in[0];
    const float* gamma = (const float*)d_in[1];
    const float* beta  = (const float*)d_in[2];
    const float* w_t   = (const float*)d_in[3];
    const float* b_t   = (const float*)d_in[4];
    const float* w_s   = (const float*)d_in[5];
    const float* b_s   = (const float*)d_in[6];
    const float* w_r   = (const float*)d_in[7];
    const float* b_r   = (const float*)d_in[8];
    const float* w_g   = (const float*)d_in[9];
    const float* b_g   = (const float*)d_in[10];
    float* out = (float*)d_out;
    float* ws  = (float*)d_ws;

    transpose_kernel<<<16, 256, 0, stream>>>(w_g, ws);
    fused_kernel<<<BB * CC, 256, 0, stream>>>(
        dx, gamma, beta, w_t, b_t, w_s, b_s, w_r, b_r, b_g, ws, out);
}

// Round 14
// 65.260 us; speedup vs baseline: 1.1928x; 1.0218x over previous
//
#include <hip/hip_runtime.h>
#include <math.h>

// Problem constants (match reference)
#define BB   16
#define CC   64
#define LL   512
#define LP   16
#define DM   1024
#define NP   64
#define PRD  256   // period = L/2
#define HEAD 128   // PRD/2
#define NV   256   // L - PRD

typedef float f32x4 __attribute__((ext_vector_type(4)));

// ---------------------------------------------------------------------------
// Single fused kernel: one block per (b,c).
// In-block coalesced channel stats -> transform -> scan decompose ->
// 48 features -> coalesced-row matvec vs UNtransposed w_g (quad-reduce) ->
// per-wave contiguous broadcast stores. One dispatch, no workspace.
// ---------------------------------------------------------------------------
__global__ __launch_bounds__(256) void fused_kernel(
    const float* __restrict__ dx,    const float* __restrict__ gamma,
    const float* __restrict__ beta,  const float* __restrict__ w_t,
    const float* __restrict__ b_t,   const float* __restrict__ w_s,
    const float* __restrict__ b_s,   const float* __restrict__ w_r,
    const float* __restrict__ b_r,   const float* __restrict__ w_g,
    const float* __restrict__ b_g,   float* __restrict__ out)
{
    __shared__ __align__(16) float xs[LL];
    __shared__ __align__(16) float pps[LL/2 + 1];
    __shared__ __align__(16) float tvs[NV];
    __shared__ __align__(16) float pas[PRD];
    __shared__ __align__(16) float feats[48];
    __shared__ __align__(16) float sres[DM];
    __shared__ float wsum[4];
    __shared__ float wred[4];

    const int tid  = threadIdx.x;
    const int lane = tid & 63;
    const int wv   = tid >> 6;
    const int bc   = blockIdx.x;
    const int b    = bc >> 6;
    const int cown = bc & 63;

    // ---- in-block channel stats (coalesced): thread owns l = 2tid, 2tid+1.
    const float2* dxb = (const float2*)(dx + (size_t)b * CC * LL);
    float2 sv = make_float2(0.f, 0.f), qv = make_float2(0.f, 0.f);
    float2 xv = make_float2(0.f, 0.f);
#pragma unroll 8
    for (int c = 0; c < CC; ++c) {
        float2 v = dxb[c * 256 + tid];
        if (c == cown) xv = v;
        sv.x += v.x;       sv.y += v.y;
        qv.x += v.x * v.x; qv.y += v.y * v.y;
    }
    float2 mp;
    {
        float mx = sv.x * (1.0f / CC), my = sv.y * (1.0f / CC);
        float vx = (qv.x - (float)CC * mx * mx) * (1.0f / (CC - 1));
        float vy = (qv.y - (float)CC * my * my) * (1.0f / (CC - 1));
        mp.x = mx / sqrtf(vx);
        mp.y = my / sqrtf(vy);
    }

    // ---- transform (float2): x = gamma*(dx - meanp) + beta
    const size_t base = (size_t)bc * LL;
    float2 gv = ((const float2*)(gamma + base))[tid];
    float2 bv = ((const float2*)(beta  + base))[tid];
    float2 xp;
    xp.x = gv.x * (xv.x - mp.x) + bv.x;
    xp.y = gv.y * (xv.y - mp.y) + bv.y;
    ((float2*)xs)[tid] = xp;

    // ---- inclusive scan of pair-sums (256 pairs)
    float v = xp.x + xp.y;
#pragma unroll
    for (int d = 1; d < 64; d <<= 1) {
        float t = __shfl_up(v, d, 64);
        if (lane >= d) v += t;
    }
    if (lane == 63) wsum[wv] = v;
    __syncthreads();
    float off = 0.f;
    for (int w = 0; w < wv; ++w) off += wsum[w];
    pps[tid + 1] = v + off;
    if (tid == 0) pps[0] = 0.f;
    __syncthreads();

    // ---- trend via prefix sums
    const int i  = tid;
    const int k2 = i + 257;
    const float Pi = pps[i  >> 1] + ((i  & 1) ? xs[i  & ~1] : 0.f);
    const float Pk = pps[k2 >> 1] + ((k2 & 1) ? xs[k2 & ~1] : 0.f);
    const float tv = (Pk - Pi - 0.5f * (xs[i] + xs[i + 256])) * (1.0f / 256.0f);
    tvs[i] = tv;
    const float dv = xs[HEAD + i] - tv;

    // ---- mdv = mean(dv)
    float r = dv;
#pragma unroll
    for (int m = 32; m; m >>= 1) r += __shfl_xor(r, m, 64);
    if (lane == 0) wred[wv] = r;
    __syncthreads();
    const float mdv = (wred[0] + wred[1] + wred[2] + wred[3]) * (1.0f / 256.0f);

    pas[(i + 128) & 255] = dv - mdv;
    __syncthreads();

    // ---- feature dots, direct weights
    {
        const int g  = tid >> 4;
        const int ln = tid & 15;
        const f32x4* wt4  = (const f32x4*)(w_t + g * LL + HEAD);
        const f32x4* ws4a = (const f32x4*)(w_s + g * LL);
        const f32x4* ws4b = (const f32x4*)(w_s + g * LL + PRD);
        const f32x4* wr4  = (const f32x4*)(w_r + g * LL + HEAD);
        const f32x4* tv4  = (const f32x4*)tvs;
        const f32x4* pa4  = (const f32x4*)pas;
        float at = 0.f, as = 0.f, ar = 0.f;
#pragma unroll
        for (int q = 0; q < 4; ++q) {
            const int m = ln * 4 + q;
            f32x4 t  = tv4[m],  p  = pa4[m];
            f32x4 a  = wt4[m];
            f32x4 s1 = ws4a[m], s2 = ws4b[m];
            f32x4 rr = wr4[m];
            at += t.x * a.x + t.y * a.y + t.z * a.z + t.w * a.w;
            as += p.x * (s1.x + s2.x) + p.y * (s1.y + s2.y)
                + p.z * (s1.z + s2.z) + p.w * (s1.w + s2.w);
            ar += rr.x + rr.y + rr.z + rr.w;
        }
#pragma unroll
        for (int msk = 8; msk; msk >>= 1) {
            at += __shfl_xor(at, msk, 64);
            as += __shfl_xor(as, msk, 64);
            ar += __shfl_xor(ar, msk, 64);
        }
        if (ln == 0) {
            feats[g]      = at + b_t[g];
            feats[16 + g] = as + b_s[g];
            feats[32 + g] = mdv * ar + b_r[g];
        }
    }
    __syncthreads();

    // ---- matvec vs UNtransposed w_g, coalesced row-window reads.
    // Pass p: wave wv covers rows d in [p*64 + wv*16, +16). Wave reads 768
    // consecutive floats (3 dwordx4/lane). Quad (lane&~3) owns one row;
    // lane handles j-slice [12*(lane&3), +12) with feats slice in registers.
    {
        const int qsl = lane & 3;               // j-slice selector
        float fs[12];
#pragma unroll
        for (int k = 0; k < 12; ++k) fs[k] = feats[qsl * 12 + k];

        const f32x4* wg4 = (const f32x4*)w_g;
#pragma unroll 4
        for (int p = 0; p < 16; ++p) {
            const int drow = p * 64 + wv * 16 + (lane >> 2);
            const int wbase = (p * 64 + wv * 16) * 12 + 3 * lane;
            f32x4 w0 = wg4[wbase + 0];
            f32x4 w1 = wg4[wbase + 1];
            f32x4 w2 = wg4[wbase + 2];
            float acc = fs[0]*w0.x + fs[1]*w0.y + fs[2]*w0.z + fs[3]*w0.w
                      + fs[4]*w1.x + fs[5]*w1.y + fs[6]*w1.z + fs[7]*w1.w
                      + fs[8]*w2.x + fs[9]*w2.y + fs[10]*w2.z + fs[11]*w2.w;
            acc += __shfl_xor(acc, 1, 64);
            acc += __shfl_xor(acc, 2, 64);
            if (qsl == 0) sres[drow] = acc + b_g[drow];
        }
    }
    __syncthreads();

    // ---- broadcast stores, per-wave CONTIGUOUS 64KB streams (R11 pattern)
    const f32x4* s4 = (const f32x4*)sres;
    const f32x4 v0 = s4[lane];
    const f32x4 v1 = s4[64 + lane];
    const f32x4 v2 = s4[128 + lane];
    const f32x4 v3 = s4[192 + lane];
    f32x4* op = (f32x4*)out + (size_t)bc * (NP * DM / 4)
              + (size_t)(wv * 16) * (DM / 4) + lane;
#pragma unroll
    for (int n = 0; n < 16; ++n) {
        op[n * (DM / 4) +   0] = v0;
        op[n * (DM / 4) +  64] = v1;
        op[n * (DM / 4) + 128] = v2;
        op[n * (DM / 4) + 192] = v3;
    }
}

// ---------------------------------------------------------------------------
extern "C" void kernel_launch(void* const* d_in, const int* in_sizes, int n_in,
                              void* d_out, int out_size, void* d_ws, size_t ws_size,
                              hipStream_t stream) {
    const float* dx    = (const float*)d_in[0];
    const float* gamma = (const float*)d_in[1];
    const float* beta  = (const float*)d_in[2];
    const float* w_t   = (const float*)d_in[3];
    const float* b_t   = (const float*)d_in[4];
    const float* w_s   = (const float*)d_in[5];
    const float* b_s   = (const float*)d_in[6];
    const float* w_r   = (const float*)d_in[7];
    const float* b_r   = (const float*)d_in[8];
    const float* w_g   = (const float*)d_in[9];
    const float* b_g   = (const float*)d_in[10];
    float* out = (float*)d_out;

    fused_kernel<<<BB * CC, 256, 0, stream>>>(
        dx, gamma, beta, w_t, b_t, w_s, b_s, w_r, b_r, w_g, b_g, out);
}